// Round 1
// baseline (173.088 us; speedup 1.0000x reference)
//
#include <hip/hip_runtime.h>
#include <hip/hip_bf16.h>

// CriticHead fused kernel (fp32).
//
// Math reduction from the reference:
//   feat[t] = [outer3(res,fr,estep) (150) | backbone (768)]   (matches W1 row order)
//   y2 = relu(feat @ W1 + b1)                                  [T,128]
//   y41 = y2 * mean(enode[t])        (einsum collapses to scalar)
//   y42 = y2 * (sum ccl[t])*(sum cnd[t])
//   y51 = sigmoid(me*d3 + b3), y61 = me*d4 + b4   (d3 = y2.W3, d4 = y2.W4)
//   y52 = sigmoid(sc*d5 + b5), y62 = sc*d6 + b6
//   p = y51*y52 ; y = (1-p)*(-100) + p*(y61+y62)
//
// Layout: 256 blocks x 512 threads. Block = 16 tasks. Thread (kq = t&31,
// rsub = t>>5) owns k = 4*kq..4*kq+3 for task = block*16 + rsub.
// Outer-150 segment staged in LDS; backbone segment read straight from
// global (wave-uniform float4 -> 1 request/half-wave, backbone read once).

#define FAILC -100.0f

__global__ __launch_bounds__(512) void critic_fused(
    const float* __restrict__ bb,     // [T,768]
    const float* __restrict__ res,    // [T,5]
    const float* __restrict__ fr,     // [T,5]
    const float* __restrict__ estep,  // [T,6]
    const float* __restrict__ enode,  // [T,64]
    const float* __restrict__ ccl,    // [T,4]
    const float* __restrict__ cnd,    // [T,32]
    const float* __restrict__ W1,     // [918,128]
    const float* __restrict__ b1,     // [128]
    const float* __restrict__ W3,     // [128]
    const float* __restrict__ b3,     // [1]
    const float* __restrict__ W4,     // [128]
    const float* __restrict__ b4,     // [1]
    const float* __restrict__ W5,     // [128]
    const float* __restrict__ b5,     // [1]
    const float* __restrict__ W6,     // [128]
    const float* __restrict__ b6,     // [1]
    float* __restrict__ out)          // [T]
{
    __shared__ float s_small[16][16];   // per task: res(5) fr(5) estep(6)
    __shared__ float s_feat[16][152];   // outer 150 + 2 zero pad (152%32=24 -> no bank clash)

    const int t = threadIdx.x;
    const int task0 = blockIdx.x * 16;

    // ---- stage the small vectors ----
    if (t < 256) {
        int r = t >> 4, q = t & 15;
        int tg = task0 + r;
        float v;
        if (q < 5)       v = res[tg * 5 + q];
        else if (q < 10) v = fr[tg * 5 + (q - 5)];
        else             v = estep[tg * 6 + (q - 10)];
        s_small[r][q] = v;
    }
    __syncthreads();

    // ---- build outer-product features (150 per task) + zero pad ----
    for (int w = t; w < 2432; w += 512) {
        if (w < 2400) {
            int r = w / 150;
            int idx = w - r * 150;
            int n = idx / 30;
            int rem = idx - n * 30;
            int m = rem / 6;
            int o = rem - m * 6;
            s_feat[r][idx] = s_small[r][n] * s_small[r][5 + m] * s_small[r][10 + o];
        } else {
            int z = w - 2400;            // 0..31
            s_feat[z >> 1][150 + (z & 1)] = 0.0f;
        }
    }
    __syncthreads();

    // ---- fc1: thread computes y2[tg][4kq..4kq+3] ----
    const int kq = t & 31;
    const int rsub = t >> 5;
    const int tg = task0 + rsub;
    const int k4 = kq * 4;

    float acc0 = 0.f, acc1 = 0.f, acc2 = 0.f, acc3 = 0.f;

    // Segment A: W1 rows 0..151 vs s_feat (rows 150,151 are zero-padded,
    // their true contribution comes from segment B which starts at row 150).
    #pragma unroll 2
    for (int p = 0; p < 152; p += 4) {
        float4 f = *(const float4*)&s_feat[rsub][p];
        float4 w0 = *(const float4*)(W1 + (p + 0) * 128 + k4);
        float4 w1 = *(const float4*)(W1 + (p + 1) * 128 + k4);
        float4 w2 = *(const float4*)(W1 + (p + 2) * 128 + k4);
        float4 w3 = *(const float4*)(W1 + (p + 3) * 128 + k4);
        acc0 += f.x * w0.x + f.y * w1.x + f.z * w2.x + f.w * w3.x;
        acc1 += f.x * w0.y + f.y * w1.y + f.z * w2.y + f.w * w3.y;
        acc2 += f.x * w0.z + f.y * w1.z + f.z * w2.z + f.w * w3.z;
        acc3 += f.x * w0.w + f.y * w1.w + f.z * w2.w + f.w * w3.w;
    }

    // Segment B: W1 rows 150..917 vs backbone (wave-uniform float4 loads).
    const float* bbrow = bb + (size_t)tg * 768;
    #pragma unroll 4
    for (int m = 0; m < 192; ++m) {
        float4 f = *(const float4*)(bbrow + 4 * m);
        int p = 150 + 4 * m;
        float4 w0 = *(const float4*)(W1 + (p + 0) * 128 + k4);
        float4 w1 = *(const float4*)(W1 + (p + 1) * 128 + k4);
        float4 w2 = *(const float4*)(W1 + (p + 2) * 128 + k4);
        float4 w3 = *(const float4*)(W1 + (p + 3) * 128 + k4);
        acc0 += f.x * w0.x + f.y * w1.x + f.z * w2.x + f.w * w3.x;
        acc1 += f.x * w0.y + f.y * w1.y + f.z * w2.y + f.w * w3.y;
        acc2 += f.x * w0.z + f.y * w1.z + f.z * w2.z + f.w * w3.z;
        ac3:
        acc3 += f.x * w0.w + f.y * w1.w + f.z * w2.w + f.w * w3.w;
    }

    // ---- bias + relu ----
    float y0 = fmaxf(acc0 + b1[k4 + 0], 0.f);
    float y1 = fmaxf(acc1 + b1[k4 + 1], 0.f);
    float y2v = fmaxf(acc2 + b1[k4 + 2], 0.f);
    float y3 = fmaxf(acc3 + b1[k4 + 3], 0.f);

    // ---- head dot-product partials ----
    float4 w3v = *(const float4*)(W3 + k4);
    float4 w4v = *(const float4*)(W4 + k4);
    float4 w5v = *(const float4*)(W5 + k4);
    float4 w6v = *(const float4*)(W6 + k4);
    float pd3 = y0 * w3v.x + y1 * w3v.y + y2v * w3v.z + y3 * w3v.w;
    float pd4 = y0 * w4v.x + y1 * w4v.y + y2v * w4v.z + y3 * w4v.w;
    float pd5 = y0 * w5v.x + y1 * w5v.y + y2v * w5v.z + y3 * w5v.w;
    float pd6 = y0 * w6v.x + y1 * w6v.y + y2v * w6v.z + y3 * w6v.w;

    // scalar reductions for enode mean / ccl / cnd sums
    const float* en = enode + (size_t)tg * 64 + kq * 2;
    float pe = en[0] + en[1];
    float pc = (kq < 4) ? ccl[tg * 4 + kq] : 0.f;
    float pn = cnd[tg * 32 + kq];

    // ---- half-wave (32-lane) reduction; xor masks < 32 stay in half ----
    #pragma unroll
    for (int m = 1; m < 32; m <<= 1) {
        pd3 += __shfl_xor(pd3, m);
        pd4 += __shfl_xor(pd4, m);
        pd5 += __shfl_xor(pd5, m);
        pd6 += __shfl_xor(pd6, m);
        pe  += __shfl_xor(pe, m);
        pc  += __shfl_xor(pc, m);
        pn  += __shfl_xor(pn, m);
    }

    if (kq == 0) {
        float me = pe * (1.0f / 64.0f);
        float sc = pc * pn;
        float a3 = me * pd3 + b3[0];
        float a5 = sc * pd5 + b5[0];
        float y51 = 1.0f / (1.0f + __expf(-a3));
        float y52 = 1.0f / (1.0f + __expf(-a5));
        float y61 = me * pd4 + b4[0];
        float y62 = sc * pd6 + b6[0];
        float p = y51 * y52;
        out[tg] = (1.0f - p) * FAILC + p * (y61 + y62);
    }
}

extern "C" void kernel_launch(void* const* d_in, const int* in_sizes, int n_in,
                              void* d_out, int out_size, void* d_ws, size_t ws_size,
                              hipStream_t stream) {
    const float* bb    = (const float*)d_in[2];
    const float* res   = (const float*)d_in[3];
    const float* fr    = (const float*)d_in[4];
    const float* estep = (const float*)d_in[5];
    const float* enode = (const float*)d_in[6];
    const float* ccl   = (const float*)d_in[7];
    const float* cnd   = (const float*)d_in[8];
    const float* W1    = (const float*)d_in[9];
    const float* b1    = (const float*)d_in[10];
    const float* W3    = (const float*)d_in[11];
    const float* b3    = (const float*)d_in[12];
    const float* W4    = (const float*)d_in[13];
    const float* b4    = (const float*)d_in[14];
    const float* W5    = (const float*)d_in[15];
    const float* b5    = (const float*)d_in[16];
    const float* W6    = (const float*)d_in[17];
    const float* b6    = (const float*)d_in[18];
    float* out = (float*)d_out;

    int T = in_sizes[3] / 5;      // y_res is [T,5]
    int blocks = T / 16;          // 16 tasks per block

    hipLaunchKernelGGL(critic_fused, dim3(blocks), dim3(512), 0, stream,
                       bb, res, fr, estep, enode, ccl, cnd,
                       W1, b1, W3, b3, W4, b4, W5, b5, W6, b6, out);
}

// Round 2
// 105.869 us; speedup vs baseline: 1.6349x; 1.6349x over previous
//
#include <hip/hip_runtime.h>
#include <hip/hip_bf16.h>

// CriticHead fused, round 2: bf16 MFMA for fc1.
//
// Math (verified in R1, absmax 0):
//   feat[t] = [outer3(res,fr,estep)(150) | backbone(768)]  (W1 row order)
//   y2 = relu(feat @ W1 + b1);  y41 = y2*mean(enode);  y42 = y2*(sum ccl)(sum cnd)
//   heads -> y = (1-p)*(-100) + p*(y61+y62), p = sig(me*d3+b3)*sig(sc*d5+b5)
//
// R1 was latency-bound (VALUBusy 10%, HBM 1%, 2 waves/SIMD on an L2 W1 stream).
// R2: fc1 via mfma_f32_16x16x32_bf16. K permuted to [bb(768)|outer(150)|pad(10)]
// (for LDS alignment); kernel 1 writes W1 as bf16 in B-fragment order into d_ws
// so kernel 2's B load is one coalesced 16B/lane read. A (feat) staged bf16 in
// LDS. 256 blocks x 512 thr; wave w owns col-tile n0=16w, 29 K-chunks.

typedef __bf16  bf16x8 __attribute__((ext_vector_type(8)));
typedef float   f32x4  __attribute__((ext_vector_type(4)));
typedef unsigned int uintx4 __attribute__((ext_vector_type(4)));
typedef unsigned short ushort4e __attribute__((ext_vector_type(4)));

#define FAILC -100.0f
#define KP 928              // padded K (29 * 32)
#define ASTRIDE 936         // LDS row stride in bf16 (468 dwords; 16B aligned rows)

static __device__ __forceinline__ unsigned short f2bf(float f) {
    unsigned u = __builtin_bit_cast(unsigned, f);
    u = (u + 0x7FFFu + ((u >> 16) & 1u)) >> 16;   // RNE
    return (unsigned short)u;
}

// ---- kernel 1: W1 fp32 -> bf16, permuted K, B-fragment-swizzled into ws ----
// frag element j of (c,h,lane): B[k=32c+(lane>>4)*8+j][n=16h+(lane&15)]
// with k in permuted order: k<768 -> W1 row 150+k; 768<=k<918 -> row k-768; else 0.
__global__ __launch_bounds__(256) void critic_prep(
    const float* __restrict__ W1, unsigned short* __restrict__ wsB)
{
    int tid = blockIdx.x * 256 + threadIdx.x;   // 29*8*64 = 14848 total
    int l = tid & 63;
    int h = (tid >> 6) & 7;
    int c = tid >> 9;
    int n = h * 16 + (l & 15);
    int kbase = c * 32 + (l >> 4) * 8;
    unsigned short v[8];
#pragma unroll
    for (int j = 0; j < 8; ++j) {
        int p = kbase + j;
        float f;
        if (p < 768)      f = W1[(size_t)(150 + p) * 128 + n];
        else if (p < 918) f = W1[(size_t)(p - 768) * 128 + n];
        else              f = 0.0f;
        v[j] = f2bf(f);
    }
    uintx4 pk;
    pk.x = (unsigned)v[0] | ((unsigned)v[1] << 16);
    pk.y = (unsigned)v[2] | ((unsigned)v[3] << 16);
    pk.z = (unsigned)v[4] | ((unsigned)v[5] << 16);
    pk.w = (unsigned)v[6] | ((unsigned)v[7] << 16);
    *(uintx4*)(wsB + (size_t)tid * 8) = pk;
}

// ---- kernel 2: fused main ----
__global__ __launch_bounds__(512) void critic_main(
    const float* __restrict__ bb,     // [T,768]
    const float* __restrict__ res,    // [T,5]
    const float* __restrict__ fr,     // [T,5]
    const float* __restrict__ estep,  // [T,6]
    const float* __restrict__ enode,  // [T,64]
    const float* __restrict__ ccl,    // [T,4]
    const float* __restrict__ cnd,    // [T,32]
    const unsigned short* __restrict__ wsB,  // swizzled bf16 W1
    const float* __restrict__ b1,     // [128]
    const float* __restrict__ W3, const float* __restrict__ b3,
    const float* __restrict__ W4, const float* __restrict__ b4,
    const float* __restrict__ W5, const float* __restrict__ b5,
    const float* __restrict__ W6, const float* __restrict__ b6,
    float* __restrict__ out)          // [T]
{
    __shared__ unsigned short a_lds[16 * ASTRIDE];  // bf16 feat, K-permuted
    __shared__ float s_y2[16][132];                 // relu(fc1) fp32
    __shared__ float s_small[16][16];               // res(5) fr(5) estep(6)

    const int t = threadIdx.x;
    const int task0 = blockIdx.x * 16;

    // stage small vectors
    if (t < 256) {
        int r = t >> 4, q = t & 15;
        int tg = task0 + r;
        float v;
        if (q < 5)       v = res[tg * 5 + q];
        else if (q < 10) v = fr[tg * 5 + (q - 5)];
        else             v = estep[tg * 6 + (q - 10)];
        s_small[r][q] = v;
    }

    // stage backbone -> bf16 LDS cols [0,768). 3072 float4s, 6 per thread.
    {
        const float4* bbp = (const float4*)(bb + (size_t)task0 * 768);
#pragma unroll
        for (int it = 0; it < 6; ++it) {
            int i = t + it * 512;          // 0..3071
            int m = i / 192;               // task row
            int off = (i - m * 192) * 4;   // col in [0,768)
            float4 v = bbp[i];
            ushort4e pk = { f2bf(v.x), f2bf(v.y), f2bf(v.z), f2bf(v.w) };
            *(ushort4e*)&a_lds[m * ASTRIDE + off] = pk;
        }
    }
    __syncthreads();

    // outer products -> cols [768,918); zero pad cols [918,928)
    for (int w = t; w < 2560; w += 512) {
        if (w < 2400) {
            int r = w / 150;
            int idx = w - r * 150;
            int n = idx / 30;
            int rem = idx - n * 30;
            int m = rem / 6;
            int o = rem - m * 6;
            float v = s_small[r][n] * s_small[r][5 + m] * s_small[r][10 + o];
            a_lds[r * ASTRIDE + 768 + idx] = f2bf(v);
        } else {
            int z = w - 2400;              // 0..159
            int r = z / 10;
            a_lds[r * ASTRIDE + 918 + (z - r * 10)] = 0;
        }
    }
    __syncthreads();

    // ---- MFMA main loop: wave w computes D[16 tasks][16 cols], n0 = 16w ----
    const int lane = t & 63;
    const int wave = t >> 6;
    const int mrow = lane & 15;
    const int quad = lane >> 4;

    const unsigned short* aptr = a_lds + mrow * ASTRIDE + quad * 8;
    const unsigned short* bptr = wsB + (size_t)(wave * 64 + lane) * 8;

    f32x4 acc = {0.f, 0.f, 0.f, 0.f};
    uintx4 bnext = *(const uintx4*)bptr;
#pragma unroll
    for (int c = 0; c < 29; ++c) {
        uintx4 bcur = bnext;
        if (c < 28) bnext = *(const uintx4*)(bptr + (size_t)(c + 1) * 4096);
        uintx4 au = *(const uintx4*)(aptr + c * 32);
        acc = __builtin_amdgcn_mfma_f32_16x16x32_bf16(
            __builtin_bit_cast(bf16x8, au), __builtin_bit_cast(bf16x8, bcur),
            acc, 0, 0, 0);
    }

    // epilogue: bias + relu -> s_y2.  D layout: col=lane&15, row=quad*4+reg.
    {
        int n = wave * 16 + mrow;
        float bias = b1[n];
#pragma unroll
        for (int r = 0; r < 4; ++r) {
            int m = quad * 4 + r;
            s_y2[m][n] = fmaxf(acc[r] + bias, 0.f);
        }
    }
    __syncthreads();

    // ---- heads (identical math to R1, which validated absmax 0) ----
    const int kq = t & 31;
    const int rsub = t >> 5;
    const int tg = task0 + rsub;
    const int k4 = kq * 4;

    float4 yv = *(const float4*)&s_y2[rsub][k4];
    float y0 = yv.x, y1 = yv.y, y2v = yv.z, y3 = yv.w;

    float4 w3v = *(const float4*)(W3 + k4);
    float4 w4v = *(const float4*)(W4 + k4);
    float4 w5v = *(const float4*)(W5 + k4);
    float4 w6v = *(const float4*)(W6 + k4);
    float pd3 = y0 * w3v.x + y1 * w3v.y + y2v * w3v.z + y3 * w3v.w;
    float pd4 = y0 * w4v.x + y1 * w4v.y + y2v * w4v.z + y3 * w4v.w;
    float pd5 = y0 * w5v.x + y1 * w5v.y + y2v * w5v.z + y3 * w5v.w;
    float pd6 = y0 * w6v.x + y1 * w6v.y + y2v * w6v.z + y3 * w6v.w;

    const float* en = enode + (size_t)tg * 64 + kq * 2;
    float pe = en[0] + en[1];
    float pc = (kq < 4) ? ccl[tg * 4 + kq] : 0.f;
    float pn = cnd[tg * 32 + kq];

#pragma unroll
    for (int m = 1; m < 32; m <<= 1) {
        pd3 += __shfl_xor(pd3, m);
        pd4 += __shfl_xor(pd4, m);
        pd5 += __shfl_xor(pd5, m);
        pd6 += __shfl_xor(pd6, m);
        pe  += __shfl_xor(pe, m);
        pc  += __shfl_xor(pc, m);
        pn  += __shfl_xor(pn, m);
    }

    if (kq == 0) {
        float me = pe * (1.0f / 64.0f);
        float sc = pc * pn;
        float a3 = me * pd3 + b3[0];
        float a5 = sc * pd5 + b5[0];
        float y51 = 1.0f / (1.0f + __expf(-a3));
        float y52 = 1.0f / (1.0f + __expf(-a5));
        float y61 = me * pd4 + b4[0];
        float y62 = sc * pd6 + b6[0];
        float p = y51 * y52;
        out[tg] = (1.0f - p) * FAILC + p * (y61 + y62);
    }
}

extern "C" void kernel_launch(void* const* d_in, const int* in_sizes, int n_in,
                              void* d_out, int out_size, void* d_ws, size_t ws_size,
                              hipStream_t stream) {
    const float* bb    = (const float*)d_in[2];
    const float* res   = (const float*)d_in[3];
    const float* fr    = (const float*)d_in[4];
    const float* estep = (const float*)d_in[5];
    const float* enode = (const float*)d_in[6];
    const float* ccl   = (const float*)d_in[7];
    const float* cnd   = (const float*)d_in[8];
    const float* W1    = (const float*)d_in[9];
    const float* b1    = (const float*)d_in[10];
    const float* W3    = (const float*)d_in[11];
    const float* b3    = (const float*)d_in[12];
    const float* W4    = (const float*)d_in[13];
    const float* b4    = (const float*)d_in[14];
    const float* W5    = (const float*)d_in[15];
    const float* b5    = (const float*)d_in[16];
    const float* W6    = (const float*)d_in[17];
    const float* b6    = (const float*)d_in[18];
    float* out = (float*)d_out;
    unsigned short* wsB = (unsigned short*)d_ws;   // 237,568 B used

    int T = in_sizes[3] / 5;      // y_res is [T,5]
    int blocks = T / 16;          // 16 tasks per block

    hipLaunchKernelGGL(critic_prep, dim3(58), dim3(256), 0, stream, W1, wsB);
    hipLaunchKernelGGL(critic_main, dim3(blocks), dim3(512), 0, stream,
                       bb, res, fr, estep, enode, ccl, cnd,
                       wsB, b1, W3, b3, W4, b4, W5, b5, W6, b6, out);
}